// Round 1
// baseline (404.448 us; speedup 1.0000x reference)
//
#include <hip/hip_runtime.h>
#include <hip/hip_bf16.h>

#define B_  4
#define T_  2048
#define C_  1024
#define H_  16
#define D_  64
#define BH_ (B_*H_)

typedef float  f32x4  __attribute__((ext_vector_type(4)));
typedef __bf16 bf16x8 __attribute__((ext_vector_type(8)));

static __device__ __forceinline__ ushort f2bf(float f) {
    union { float f; unsigned u; } x; x.f = f;
    unsigned r = ((x.u >> 16) & 1u) + 0x7fffu;
    return (ushort)((x.u + r) >> 16);
}

static __device__ __forceinline__ void gload_lds16(const void* g, void* l) {
    __builtin_amdgcn_global_load_lds(
        (const __attribute__((address_space(1))) unsigned int*)g,
        (__attribute__((address_space(3))) unsigned int*)l, 16, 0, 0);
}

// ---------------- fp32 -> bf16 elementwise (n % 4 == 0) ----------------
__global__ void cvt_kernel(const float* __restrict__ in, ushort* __restrict__ out, int n) {
    int i = (blockIdx.x * blockDim.x + threadIdx.x) * 4;
    if (i < n) {
        float4 v = *(const float4*)(in + i);
        ushort4 o;
        o.x = f2bf(v.x); o.y = f2bf(v.y); o.z = f2bf(v.z); o.w = f2bf(v.w);
        *(ushort4*)(out + i) = o;
    }
}

// ---------------- W (K x N fp32) -> Wt (N x K bf16) ----------------
__global__ void transpose_cvt_kernel(const float* __restrict__ in, ushort* __restrict__ out,
                                     int K, int N) {
    __shared__ float tile[32][33];
    int k0 = blockIdx.y * 32, n0 = blockIdx.x * 32;
    int tx = threadIdx.x & 31, ty = threadIdx.x >> 5;  // 32 x 8
    #pragma unroll
    for (int r = 0; r < 32; r += 8)
        tile[ty + r][tx] = in[(size_t)(k0 + ty + r) * N + n0 + tx];
    __syncthreads();
    #pragma unroll
    for (int r = 0; r < 32; r += 8)
        out[(size_t)(n0 + ty + r) * K + k0 + tx] = f2bf(tile[tx][ty + r]);
}

// ---------------- V (bh, t, d) bf16 -> Vt (bh, d, t) bf16 ----------------
__global__ void transpose_v_kernel(const ushort* __restrict__ v, ushort* __restrict__ vt) {
    __shared__ ushort tile[64][66];
    int bh = blockIdx.x >> 5;
    int t0 = (blockIdx.x & 31) * 64;
    const ushort* src = v  + ((size_t)bh * T_ + t0) * D_;
    ushort*       dst = vt + (size_t)bh * D_ * T_ + t0;
    int tx = threadIdx.x & 63, ty = threadIdx.x >> 6;  // 64 x 4
    #pragma unroll
    for (int r = 0; r < 64; r += 4)
        tile[ty + r][tx] = src[(size_t)(ty + r) * D_ + tx];
    __syncthreads();
    #pragma unroll
    for (int r = 0; r < 64; r += 4)
        dst[(size_t)(ty + r) * T_ + tx] = tile[tx][ty + r];
}

// ---------------- GEMM1: qkv = x @ w_qkv + b, scatter to q/k/v (bh,t,d) ----------------
__global__ __launch_bounds__(256) void gemm_qkv_kernel(
    const ushort* __restrict__ A,    // 8192 x 1024 bf16
    const ushort* __restrict__ Bt,   // 3072 x 1024 bf16 (N x K)
    const float*  __restrict__ bias, // 3072 fp32
    ushort* __restrict__ qkv)        // 3 x (64, 2048, 64) bf16
{
    constexpr int K = 1024;
    __shared__ __align__(16) ushort sA[128 * 64];
    __shared__ __align__(16) ushort sB[128 * 64];
    const int m0 = blockIdx.y * 128, n0 = blockIdx.x * 128;
    const int lane = threadIdx.x & 63, wv = threadIdx.x >> 6;
    const int wm = wv >> 1, wn = wv & 1;
    const int lr = lane & 15, lh = lane >> 4;
    f32x4 acc[4][4] = {};

    for (int kt = 0; kt < K; kt += 64) {
        #pragma unroll
        for (int i = 0; i < 4; ++i) {
            int j = i * 4 + wv;
            int p = j * 64 + lane;
            int row = p >> 3, kc = (p & 7) << 3;
            gload_lds16(A  + (size_t)(m0 + row) * K + kt + kc, &sA[j * 512]);
            gload_lds16(Bt + (size_t)(n0 + row) * K + kt + kc, &sB[j * 512]);
        }
        __syncthreads();
        #pragma unroll
        for (int ks = 0; ks < 2; ++ks) {
            bf16x8 af[4], bfr[4];
            #pragma unroll
            for (int mi = 0; mi < 4; ++mi)
                af[mi] = *(const bf16x8*)&sA[(wm * 64 + mi * 16 + lr) * 64 + ks * 32 + lh * 8];
            #pragma unroll
            for (int ni = 0; ni < 4; ++ni)
                bfr[ni] = *(const bf16x8*)&sB[(wn * 64 + ni * 16 + lr) * 64 + ks * 32 + lh * 8];
            #pragma unroll
            for (int mi = 0; mi < 4; ++mi)
                #pragma unroll
                for (int ni = 0; ni < 4; ++ni)
                    acc[mi][ni] = __builtin_amdgcn_mfma_f32_16x16x32_bf16(af[mi], bfr[ni], acc[mi][ni], 0, 0, 0);
        }
        __syncthreads();
    }

    #pragma unroll
    for (int mi = 0; mi < 4; ++mi) {
        #pragma unroll
        for (int ni = 0; ni < 4; ++ni) {
            int col = n0 + wn * 64 + ni * 16 + lr;
            float bv = bias[col];
            int which = col >> 10;
            int h = (col & 1023) >> 6;
            int d = col & 63;
            #pragma unroll
            for (int r = 0; r < 4; ++r) {
                int row = m0 + wm * 64 + mi * 16 + lh * 4 + r;
                int b = row >> 11, t = row & 2047;
                float v = acc[mi][ni][r] + bv;
                if (which == 0) v *= 0.125f;  // fold 1/sqrt(64) into q
                qkv[(size_t)which * (BH_ * T_ * D_) +
                    (((size_t)(b * H_ + h)) * T_ + t) * D_ + d] = f2bf(v);
            }
        }
    }
}

// ---------------- flash attention, causal, QBLK=64 / KBLK=64 ----------------
__global__ __launch_bounds__(256) void flash_kernel(
    const ushort* __restrict__ qb,  // (bh, t, d) bf16, pre-scaled by 1/8
    const ushort* __restrict__ kb,  // (bh, t, d) bf16
    const ushort* __restrict__ vt,  // (bh, d, t) bf16
    ushort* __restrict__ ob)        // (b*t, 1024) bf16
{
    __shared__ __align__(16) ushort sK[64 * 64];
    __shared__ __align__(16) ushort sV[64 * 64];
    __shared__ __align__(16) ushort sP[4][16 * 64];
    const int bh = blockIdx.x >> 5;
    const int qt = blockIdx.x & 31;
    const int lane = threadIdx.x & 63, wv = threadIdx.x >> 6;
    const int lr = lane & 15, lh = lane >> 4;
    const int q0 = qt * 64 + wv * 16;

    const ushort* qrow = qb + ((size_t)bh * T_ + q0 + lr) * D_;
    bf16x8 qf0 = *(const bf16x8*)(qrow + lh * 8);
    bf16x8 qf1 = *(const bf16x8*)(qrow + 32 + lh * 8);

    f32x4 o[4] = {};
    float mrow[4], lsum[4];
    #pragma unroll
    for (int r = 0; r < 4; ++r) { mrow[r] = -INFINITY; lsum[r] = 0.f; }

    for (int kt = 0; kt <= qt; ++kt) {
        #pragma unroll
        for (int i = 0; i < 2; ++i) {
            int j = i * 4 + wv;
            int p = j * 64 + lane;
            int row = p >> 3, kc = (p & 7) << 3;
            gload_lds16(kb + ((size_t)bh * T_ + kt * 64 + row) * D_ + kc, &sK[j * 512]);
            gload_lds16(vt + ((size_t)bh * D_ + row) * T_ + kt * 64 + kc, &sV[j * 512]);
        }
        __syncthreads();

        f32x4 s[4];
        #pragma unroll
        for (int nt = 0; nt < 4; ++nt) {
            bf16x8 k0 = *(const bf16x8*)&sK[(nt * 16 + lr) * 64 + lh * 8];
            bf16x8 k1 = *(const bf16x8*)&sK[(nt * 16 + lr) * 64 + 32 + lh * 8];
            f32x4 a = {0.f, 0.f, 0.f, 0.f};
            a = __builtin_amdgcn_mfma_f32_16x16x32_bf16(qf0, k0, a, 0, 0, 0);
            a = __builtin_amdgcn_mfma_f32_16x16x32_bf16(qf1, k1, a, 0, 0, 0);
            s[nt] = a;
        }
        if (kt == qt) {
            #pragma unroll
            for (int nt = 0; nt < 4; ++nt)
                #pragma unroll
                for (int r = 0; r < 4; ++r)
                    if (nt * 16 + lr > wv * 16 + lh * 4 + r) s[nt][r] = -INFINITY;
        }

        ushort* P = &sP[wv][0];
        #pragma unroll
        for (int r = 0; r < 4; ++r) {
            float mx = fmaxf(fmaxf(s[0][r], s[1][r]), fmaxf(s[2][r], s[3][r]));
            #pragma unroll
            for (int dd = 1; dd < 16; dd <<= 1) mx = fmaxf(mx, __shfl_xor(mx, dd, 64));
            float mnew = fmaxf(mrow[r], mx);
            float alpha = __expf(mrow[r] - mnew);
            mrow[r] = mnew;
            float rs = 0.f;
            #pragma unroll
            for (int nt = 0; nt < 4; ++nt) {
                float p = __expf(s[nt][r] - mnew);
                s[nt][r] = p;
                rs += p;
            }
            #pragma unroll
            for (int dd = 1; dd < 16; dd <<= 1) rs += __shfl_xor(rs, dd, 64);
            lsum[r] = lsum[r] * alpha + rs;
            #pragma unroll
            for (int nt = 0; nt < 4; ++nt) o[nt][r] *= alpha;
            #pragma unroll
            for (int nt = 0; nt < 4; ++nt)
                P[(lh * 4 + r) * 64 + nt * 16 + lr] = f2bf(s[nt][r]);
        }

        #pragma unroll
        for (int ks = 0; ks < 2; ++ks) {
            bf16x8 pf = *(const bf16x8*)&P[lr * 64 + ks * 32 + lh * 8];
            #pragma unroll
            for (int nt = 0; nt < 4; ++nt) {
                bf16x8 vf = *(const bf16x8*)&sV[(nt * 16 + lr) * 64 + ks * 32 + lh * 8];
                o[nt] = __builtin_amdgcn_mfma_f32_16x16x32_bf16(pf, vf, o[nt], 0, 0, 0);
            }
        }
        __syncthreads();
    }

    const int b = bh >> 4, h = bh & 15;
    #pragma unroll
    for (int r = 0; r < 4; ++r) {
        float inv = 1.f / lsum[r];
        int q = q0 + lh * 4 + r;
        #pragma unroll
        for (int nt = 0; nt < 4; ++nt)
            ob[((size_t)b * T_ + q) * C_ + h * 64 + nt * 16 + lr] = f2bf(o[nt][r] * inv);
    }
}

// ---------------- GEMM2: out = attn @ w_out + b_out (fp32 out) ----------------
__global__ __launch_bounds__(256) void gemm_out_kernel(
    const ushort* __restrict__ A,    // 8192 x 1024 bf16
    const ushort* __restrict__ Bt,   // 1024 x 1024 bf16 (N x K)
    const float*  __restrict__ bias, // 1024 fp32
    float* __restrict__ Cout)        // 8192 x 1024 fp32
{
    constexpr int K = 1024;
    __shared__ __align__(16) ushort sA[128 * 64];
    __shared__ __align__(16) ushort sB[128 * 64];
    const int m0 = blockIdx.y * 128, n0 = blockIdx.x * 128;
    const int lane = threadIdx.x & 63, wv = threadIdx.x >> 6;
    const int wm = wv >> 1, wn = wv & 1;
    const int lr = lane & 15, lh = lane >> 4;
    f32x4 acc[4][4] = {};

    for (int kt = 0; kt < K; kt += 64) {
        #pragma unroll
        for (int i = 0; i < 4; ++i) {
            int j = i * 4 + wv;
            int p = j * 64 + lane;
            int row = p >> 3, kc = (p & 7) << 3;
            gload_lds16(A  + (size_t)(m0 + row) * K + kt + kc, &sA[j * 512]);
            gload_lds16(Bt + (size_t)(n0 + row) * K + kt + kc, &sB[j * 512]);
        }
        __syncthreads();
        #pragma unroll
        for (int ks = 0; ks < 2; ++ks) {
            bf16x8 af[4], bfr[4];
            #pragma unroll
            for (int mi = 0; mi < 4; ++mi)
                af[mi] = *(const bf16x8*)&sA[(wm * 64 + mi * 16 + lr) * 64 + ks * 32 + lh * 8];
            #pragma unroll
            for (int ni = 0; ni < 4; ++ni)
                bfr[ni] = *(const bf16x8*)&sB[(wn * 64 + ni * 16 + lr) * 64 + ks * 32 + lh * 8];
            #pragma unroll
            for (int mi = 0; mi < 4; ++mi)
                #pragma unroll
                for (int ni = 0; ni < 4; ++ni)
                    acc[mi][ni] = __builtin_amdgcn_mfma_f32_16x16x32_bf16(af[mi], bfr[ni], acc[mi][ni], 0, 0, 0);
        }
        __syncthreads();
    }

    #pragma unroll
    for (int mi = 0; mi < 4; ++mi) {
        #pragma unroll
        for (int ni = 0; ni < 4; ++ni) {
            int col = n0 + wn * 64 + ni * 16 + lr;
            float bv = bias[col];
            #pragma unroll
            for (int r = 0; r < 4; ++r) {
                int row = m0 + wm * 64 + mi * 16 + lh * 4 + r;
                Cout[(size_t)row * C_ + col] = acc[mi][ni][r] + bv;
            }
        }
    }
}

extern "C" void kernel_launch(void* const* d_in, const int* in_sizes, int n_in,
                              void* d_out, int out_size, void* d_ws, size_t ws_size,
                              hipStream_t stream) {
    const float* x     = (const float*)d_in[0];
    const float* w_qkv = (const float*)d_in[1];
    const float* b_qkv = (const float*)d_in[2];
    const float* w_out = (const float*)d_in[3];
    const float* b_out = (const float*)d_in[4];
    float* out = (float*)d_out;

    char* ws = (char*)d_ws;
    // layout (bytes):
    ushort* xb     = (ushort*)(ws + 0);           // 16 MB (aliased: attn reuses this after GEMM1)
    ushort* wqkvT  = (ushort*)(ws + 16777216);    // 6 MB
    ushort* woutT  = (ushort*)(ws + 23068672);    // 2 MB
    ushort* qkv    = (ushort*)(ws + 25165824);    // 48 MB (q,k,v each 16 MB)
    ushort* vT     = (ushort*)(ws + 75497472);    // 16 MB
    ushort* attn   = xb;                          // alias: xb dead after gemm_qkv
    ushort* qb = qkv;
    ushort* kb = qkv + (size_t)BH_ * T_ * D_;
    ushort* vb = qkv + (size_t)2 * BH_ * T_ * D_;

    const int nx = B_ * T_ * C_;  // 8388608
    cvt_kernel<<<nx / 4 / 256, 256, 0, stream>>>(x, xb, nx);
    transpose_cvt_kernel<<<dim3(3 * C_ / 32, C_ / 32), 256, 0, stream>>>(w_qkv, wqkvT, C_, 3 * C_);
    transpose_cvt_kernel<<<dim3(C_ / 32, C_ / 32), 256, 0, stream>>>(w_out, woutT, C_, C_);
    gemm_qkv_kernel<<<dim3(3 * C_ / 128, B_ * T_ / 128), 256, 0, stream>>>(xb, wqkvT, b_qkv, qkv);
    transpose_v_kernel<<<BH_ * (T_ / 64), 256, 0, stream>>>(vb, vT);
    flash_kernel<<<BH_ * (T_ / 64), 256, 0, stream>>>(qb, kb, vT, attn);
    gemm_out_kernel<<<dim3(C_ / 128, B_ * T_ / 128), 256, 0, stream>>>(attn, woutT, b_out, out);
}

// Round 2
// 289.752 us; speedup vs baseline: 1.3958x; 1.3958x over previous
//
#include <hip/hip_runtime.h>
#include <hip/hip_bf16.h>

#define B_  4
#define T_  2048
#define C_  1024
#define H_  16
#define D_  64
#define BH_ (B_*H_)

typedef float  f32x4  __attribute__((ext_vector_type(4)));
typedef __bf16 bf16x8 __attribute__((ext_vector_type(8)));

static __device__ __forceinline__ ushort f2bf(float f) {
    union { float f; unsigned u; } x; x.f = f;
    unsigned r = ((x.u >> 16) & 1u) + 0x7fffu;
    return (ushort)((x.u + r) >> 16);
}

static __device__ __forceinline__ void gload_lds16(const void* g, void* l) {
    __builtin_amdgcn_global_load_lds(
        (const __attribute__((address_space(1))) unsigned int*)g,
        (__attribute__((address_space(3))) unsigned int*)l, 16, 0, 0);
}

// ---------------- fp32 -> bf16 elementwise (n % 4 == 0) ----------------
__global__ void cvt_kernel(const float* __restrict__ in, ushort* __restrict__ out, int n) {
    int i = (blockIdx.x * blockDim.x + threadIdx.x) * 4;
    if (i < n) {
        float4 v = *(const float4*)(in + i);
        ushort4 o;
        o.x = f2bf(v.x); o.y = f2bf(v.y); o.z = f2bf(v.z); o.w = f2bf(v.w);
        *(ushort4*)(out + i) = o;
    }
}

// ---------------- W (K x N fp32) -> Wt (N x K bf16) ----------------
__global__ void transpose_cvt_kernel(const float* __restrict__ in, ushort* __restrict__ out,
                                     int K, int N) {
    __shared__ float tile[32][33];
    int k0 = blockIdx.y * 32, n0 = blockIdx.x * 32;
    int tx = threadIdx.x & 31, ty = threadIdx.x >> 5;  // 32 x 8
    #pragma unroll
    for (int r = 0; r < 32; r += 8)
        tile[ty + r][tx] = in[(size_t)(k0 + ty + r) * N + n0 + tx];
    __syncthreads();
    #pragma unroll
    for (int r = 0; r < 32; r += 8)
        out[(size_t)(n0 + ty + r) * K + k0 + tx] = f2bf(tile[tx][ty + r]);
}

// ---------------- V (bh, t, d) bf16 -> Vt (bh, d, t) bf16 ----------------
__global__ void transpose_v_kernel(const ushort* __restrict__ v, ushort* __restrict__ vt) {
    __shared__ ushort tile[64][66];
    int bh = blockIdx.x >> 5;
    int t0 = (blockIdx.x & 31) * 64;
    const ushort* src = v  + ((size_t)bh * T_ + t0) * D_;
    ushort*       dst = vt + (size_t)bh * D_ * T_ + t0;
    int tx = threadIdx.x & 63, ty = threadIdx.x >> 6;  // 64 x 4
    #pragma unroll
    for (int r = 0; r < 64; r += 4)
        tile[ty + r][tx] = src[(size_t)(ty + r) * D_ + tx];
    __syncthreads();
    #pragma unroll
    for (int r = 0; r < 64; r += 4)
        dst[(size_t)(ty + r) * T_ + tx] = tile[tx][ty + r];
}

// ---------------- GEMM1: qkv = x @ w_qkv + b, scatter to q/k/v (bh,t,d) ----------------
__global__ __launch_bounds__(256) void gemm_qkv_kernel(
    const ushort* __restrict__ A,    // 8192 x 1024 bf16
    const ushort* __restrict__ Bt,   // 3072 x 1024 bf16 (N x K)
    const float*  __restrict__ bias, // 3072 fp32
    ushort* __restrict__ qkv)        // 3 x (64, 2048, 64) bf16
{
    constexpr int K = 1024;
    __shared__ __align__(16) ushort sA[128 * 64];
    __shared__ __align__(16) ushort sB[128 * 64];
    const int m0 = blockIdx.y * 128, n0 = blockIdx.x * 128;
    const int lane = threadIdx.x & 63, wv = threadIdx.x >> 6;
    const int wm = wv >> 1, wn = wv & 1;
    const int lr = lane & 15, lh = lane >> 4;
    f32x4 acc[4][4] = {};

    for (int kt = 0; kt < K; kt += 64) {
        #pragma unroll
        for (int i = 0; i < 4; ++i) {
            int j = i * 4 + wv;
            int p = j * 64 + lane;
            int row = p >> 3, kc = (p & 7) << 3;
            gload_lds16(A  + (size_t)(m0 + row) * K + kt + kc, &sA[j * 512]);
            gload_lds16(Bt + (size_t)(n0 + row) * K + kt + kc, &sB[j * 512]);
        }
        __syncthreads();
        #pragma unroll
        for (int ks = 0; ks < 2; ++ks) {
            bf16x8 af[4], bfr[4];
            #pragma unroll
            for (int mi = 0; mi < 4; ++mi)
                af[mi] = *(const bf16x8*)&sA[(wm * 64 + mi * 16 + lr) * 64 + ks * 32 + lh * 8];
            #pragma unroll
            for (int ni = 0; ni < 4; ++ni)
                bfr[ni] = *(const bf16x8*)&sB[(wn * 64 + ni * 16 + lr) * 64 + ks * 32 + lh * 8];
            #pragma unroll
            for (int mi = 0; mi < 4; ++mi)
                #pragma unroll
                for (int ni = 0; ni < 4; ++ni)
                    acc[mi][ni] = __builtin_amdgcn_mfma_f32_16x16x32_bf16(af[mi], bfr[ni], acc[mi][ni], 0, 0, 0);
        }
        __syncthreads();
    }

    #pragma unroll
    for (int mi = 0; mi < 4; ++mi) {
        #pragma unroll
        for (int ni = 0; ni < 4; ++ni) {
            int col = n0 + wn * 64 + ni * 16 + lr;
            float bv = bias[col];
            int which = col >> 10;
            int h = (col & 1023) >> 6;
            int d = col & 63;
            #pragma unroll
            for (int r = 0; r < 4; ++r) {
                int row = m0 + wm * 64 + mi * 16 + lh * 4 + r;
                int b = row >> 11, t = row & 2047;
                float v = acc[mi][ni][r] + bv;
                if (which == 0) v *= 0.18033688011112042f;  // 1/sqrt(64) * log2(e) folded into q
                qkv[(size_t)which * (BH_ * T_ * D_) +
                    (((size_t)(b * H_ + h)) * T_ + t) * D_ + d] = f2bf(v);
            }
        }
    }
}

// ---------------- flash attention v2: swapped QK^T, swizzled LDS, dbuf ----------------
// q pre-scaled by log2(e)/8 -> softmax in exp2 space.
__global__ __launch_bounds__(256) void flash_kernel(
    const ushort* __restrict__ qb,  // (bh, t, d) bf16
    const ushort* __restrict__ kb,  // (bh, t, d) bf16
    const ushort* __restrict__ vt,  // (bh, d, t) bf16
    ushort* __restrict__ ob)        // (b*t, 1024) bf16
{
    __shared__ __align__(16) ushort sK[2][64 * 64];
    __shared__ __align__(16) ushort sV[2][64 * 64];
    __shared__ __align__(16) ushort sP[4][16 * 64];
    const int bh = blockIdx.x >> 5;
    const int qt = 31 - (blockIdx.x & 31);   // long blocks first
    const int lane = threadIdx.x & 63, wv = threadIdx.x >> 6;
    const int lr = lane & 15, lh = lane >> 4;
    const int q0 = qt * 64 + wv * 16;

    // Q fragments (B-operand): lane lr holds q-row q0+lr, k = lh*8+j
    const ushort* qrow = qb + ((size_t)bh * T_ + q0 + lr) * D_;
    bf16x8 qf0 = *(const bf16x8*)(qrow + lh * 8);
    bf16x8 qf1 = *(const bf16x8*)(qrow + 32 + lh * 8);

    // staging: chunk j covers LDS rows j*8..j*8+7; lane -> row j*8+(lane>>3),
    // source col pre-swizzled so linear LDS dest == swizzled layout (rule #21)
    const int srow = lane >> 3;
    const int scol = ((lane & 7) ^ srow) * 8;
    const ushort* kbase = kb + (size_t)bh * T_ * D_;
    const ushort* vbase = vt + (size_t)bh * D_ * T_;

    // read-side swizzle: all rows read have row%8 == lr%8
    const int sw   = (lr & 7) << 4;           // byte XOR
    const int off0 = (16 * lh) ^ sw;          // k-bytes [0,32)
    const int off1 = (64 + 16 * lh) ^ sw;     // k-bytes [32,64)

    f32x4 o[4] = {};
    float mrow = -1e30f, lsum = 0.f;          // for q = q0 + lr (exp2 space)

    // prologue: stage tile 0
    #pragma unroll
    for (int i = 0; i < 2; ++i) {
        int j = i * 4 + wv;
        gload_lds16(kbase + (size_t)(j * 8 + srow) * D_ + scol, &sK[0][j * 512]);
        gload_lds16(vbase + (size_t)(j * 8 + srow) * T_ + scol, &sV[0][j * 512]);
    }
    __syncthreads();

    for (int kt = 0; kt <= qt; ++kt) {
        const int cur = kt & 1;
        if (kt < qt) {
            const int nb = cur ^ 1;
            #pragma unroll
            for (int i = 0; i < 2; ++i) {
                int j = i * 4 + wv;
                gload_lds16(kbase + (size_t)((kt + 1) * 64 + j * 8 + srow) * D_ + scol, &sK[nb][j * 512]);
                gload_lds16(vbase + (size_t)(j * 8 + srow) * T_ + (kt + 1) * 64 + scol, &sV[nb][j * 512]);
            }
        }

        // --- QK^T swapped: S^T[k][q], lane holds q=lr, k = 16nt+4lh+r ---
        const char* K0 = (const char*)sK[cur];
        f32x4 s[4];
        #pragma unroll
        for (int nt = 0; nt < 4; ++nt) {
            const char* krow = K0 + (nt * 16 + lr) * 128;
            bf16x8 k0 = *(const bf16x8*)(krow + off0);
            bf16x8 k1 = *(const bf16x8*)(krow + off1);
            f32x4 a = {0.f, 0.f, 0.f, 0.f};
            a = __builtin_amdgcn_mfma_f32_16x16x32_bf16(k0, qf0, a, 0, 0, 0);
            a = __builtin_amdgcn_mfma_f32_16x16x32_bf16(k1, qf1, a, 0, 0, 0);
            s[nt] = a;
        }
        if (kt == qt) {   // causal mask on diagonal tile: k_local > q_local
            #pragma unroll
            for (int nt = 0; nt < 4; ++nt)
                #pragma unroll
                for (int r = 0; r < 4; ++r)
                    if (nt * 16 + lh * 4 + r > wv * 16 + lr) s[nt][r] = -INFINITY;
        }

        // --- row max: in-register (16 vals) + 2 shfl over lh ---
        float pmax = fmaxf(fmaxf(fmaxf(s[0][0], s[0][1]), fmaxf(s[0][2], s[0][3])),
                           fmaxf(fmaxf(s[1][0], s[1][1]), fmaxf(s[1][2], s[1][3])));
        pmax = fmaxf(pmax, fmaxf(fmaxf(fmaxf(s[2][0], s[2][1]), fmaxf(s[2][2], s[2][3])),
                                 fmaxf(fmaxf(s[3][0], s[3][1]), fmaxf(s[3][2], s[3][3]))));
        pmax = fmaxf(pmax, __shfl_xor(pmax, 16, 64));
        pmax = fmaxf(pmax, __shfl_xor(pmax, 32, 64));

        // --- defer-max (T13, THR=8 in exp2 space) ---
        if (__any(pmax > mrow + 8.f)) {
            float mnew = fmaxf(mrow, pmax);
            float al = __builtin_exp2f(mrow - mnew);
            lsum *= al;
            #pragma unroll
            for (int r = 0; r < 4; ++r) {
                float ar = __shfl(al, lh * 20 + r, 64);  // lane with lr == lh*4+r
                o[0][r] *= ar; o[1][r] *= ar; o[2][r] *= ar; o[3][r] *= ar;
            }
            mrow = mnew;
        }

        // --- exp2 + pack to bf16 pairs ---
        float rsum = 0.f;
        uint pk[8];
        #pragma unroll
        for (int nt = 0; nt < 4; ++nt) {
            float p0 = __builtin_exp2f(s[nt][0] - mrow);
            float p1 = __builtin_exp2f(s[nt][1] - mrow);
            float p2 = __builtin_exp2f(s[nt][2] - mrow);
            float p3 = __builtin_exp2f(s[nt][3] - mrow);
            rsum += (p0 + p1) + (p2 + p3);
            pk[nt * 2]     = (uint)f2bf(p0) | ((uint)f2bf(p1) << 16);
            pk[nt * 2 + 1] = (uint)f2bf(p2) | ((uint)f2bf(p3) << 16);
        }
        rsum += __shfl_xor(rsum, 16, 64);
        rsum += __shfl_xor(rsum, 32, 64);
        lsum += rsum;

        // --- P via per-wave swizzled LDS: 4x b64 write, 2x b128 read ---
        char* P = (char*)sP[wv];
        {
            char* prow = P + lr * 128;
            #pragma unroll
            for (int nt = 0; nt < 4; ++nt) {
                uint2 w; w.x = pk[nt * 2]; w.y = pk[nt * 2 + 1];
                *(uint2*)(prow + ((32 * nt + 8 * lh) ^ sw)) = w;
            }
        }
        asm volatile("" ::: "memory");
        bf16x8 pf0 = *(const bf16x8*)(P + lr * 128 + off0);
        bf16x8 pf1 = *(const bf16x8*)(P + lr * 128 + off1);

        // --- PV: O[q][d] += P * V ---
        const char* V0 = (const char*)sV[cur];
        #pragma unroll
        for (int dt = 0; dt < 4; ++dt) {
            const char* vrow = V0 + (dt * 16 + lr) * 128;
            bf16x8 v0 = *(const bf16x8*)(vrow + off0);
            bf16x8 v1 = *(const bf16x8*)(vrow + off1);
            o[dt] = __builtin_amdgcn_mfma_f32_16x16x32_bf16(pf0, v0, o[dt], 0, 0, 0);
            o[dt] = __builtin_amdgcn_mfma_f32_16x16x32_bf16(pf1, v1, o[dt], 0, 0, 0);
        }
        __syncthreads();
    }

    const int b = bh >> 4, h = bh & 15;
    float inv = 1.f / lsum;
    #pragma unroll
    for (int r = 0; r < 4; ++r) {
        float ir = __shfl(inv, lh * 20 + r, 64);
        int q = q0 + lh * 4 + r;
        #pragma unroll
        for (int dt = 0; dt < 4; ++dt)
            ob[((size_t)b * T_ + q) * C_ + h * 64 + dt * 16 + lr] = f2bf(o[dt][r] * ir);
    }
}

// ---------------- GEMM2: out = attn @ w_out + b_out (fp32 out) ----------------
__global__ __launch_bounds__(256) void gemm_out_kernel(
    const ushort* __restrict__ A,    // 8192 x 1024 bf16
    const ushort* __restrict__ Bt,   // 1024 x 1024 bf16 (N x K)
    const float*  __restrict__ bias, // 1024 fp32
    float* __restrict__ Cout)        // 8192 x 1024 fp32
{
    constexpr int K = 1024;
    __shared__ __align__(16) ushort sA[128 * 64];
    __shared__ __align__(16) ushort sB[128 * 64];
    const int m0 = blockIdx.y * 128, n0 = blockIdx.x * 128;
    const int lane = threadIdx.x & 63, wv = threadIdx.x >> 6;
    const int wm = wv >> 1, wn = wv & 1;
    const int lr = lane & 15, lh = lane >> 4;
    f32x4 acc[4][4] = {};

    for (int kt = 0; kt < K; kt += 64) {
        #pragma unroll
        for (int i = 0; i < 4; ++i) {
            int j = i * 4 + wv;
            int p = j * 64 + lane;
            int row = p >> 3, kc = (p & 7) << 3;
            gload_lds16(A  + (size_t)(m0 + row) * K + kt + kc, &sA[j * 512]);
            gload_lds16(Bt + (size_t)(n0 + row) * K + kt + kc, &sB[j * 512]);
        }
        __syncthreads();
        #pragma unroll
        for (int ks = 0; ks < 2; ++ks) {
            bf16x8 af[4], bfr[4];
            #pragma unroll
            for (int mi = 0; mi < 4; ++mi)
                af[mi] = *(const bf16x8*)&sA[(wm * 64 + mi * 16 + lr) * 64 + ks * 32 + lh * 8];
            #pragma unroll
            for (int ni = 0; ni < 4; ++ni)
                bfr[ni] = *(const bf16x8*)&sB[(wn * 64 + ni * 16 + lr) * 64 + ks * 32 + lh * 8];
            #pragma unroll
            for (int mi = 0; mi < 4; ++mi)
                #pragma unroll
                for (int ni = 0; ni < 4; ++ni)
                    acc[mi][ni] = __builtin_amdgcn_mfma_f32_16x16x32_bf16(af[mi], bfr[ni], acc[mi][ni], 0, 0, 0);
        }
        __syncthreads();
    }

    #pragma unroll
    for (int mi = 0; mi < 4; ++mi) {
        #pragma unroll
        for (int ni = 0; ni < 4; ++ni) {
            int col = n0 + wn * 64 + ni * 16 + lr;
            float bv = bias[col];
            #pragma unroll
            for (int r = 0; r < 4; ++r) {
                int row = m0 + wm * 64 + mi * 16 + lh * 4 + r;
                Cout[(size_t)row * C_ + col] = acc[mi][ni][r] + bv;
            }
        }
    }
}

extern "C" void kernel_launch(void* const* d_in, const int* in_sizes, int n_in,
                              void* d_out, int out_size, void* d_ws, size_t ws_size,
                              hipStream_t stream) {
    const float* x     = (const float*)d_in[0];
    const float* w_qkv = (const float*)d_in[1];
    const float* b_qkv = (const float*)d_in[2];
    const float* w_out = (const float*)d_in[3];
    const float* b_out = (const float*)d_in[4];
    float* out = (float*)d_out;

    char* ws = (char*)d_ws;
    ushort* xb     = (ushort*)(ws + 0);           // 16 MB (aliased: attn out reuses after GEMM1)
    ushort* wqkvT  = (ushort*)(ws + 16777216);    // 6 MB
    ushort* woutT  = (ushort*)(ws + 23068672);    // 2 MB
    ushort* qkv    = (ushort*)(ws + 25165824);    // 48 MB
    ushort* vT     = (ushort*)(ws + 75497472);    // 16 MB
    ushort* attn   = xb;
    ushort* qb = qkv;
    ushort* kb = qkv + (size_t)BH_ * T_ * D_;
    ushort* vb = qkv + (size_t)2 * BH_ * T_ * D_;

    const int nx = B_ * T_ * C_;
    cvt_kernel<<<nx / 4 / 256, 256, 0, stream>>>(x, xb, nx);
    transpose_cvt_kernel<<<dim3(3 * C_ / 32, C_ / 32), 256, 0, stream>>>(w_qkv, wqkvT, C_, 3 * C_);
    transpose_cvt_kernel<<<dim3(C_ / 32, C_ / 32), 256, 0, stream>>>(w_out, woutT, C_, C_);
    gemm_qkv_kernel<<<dim3(3 * C_ / 128, B_ * T_ / 128), 256, 0, stream>>>(xb, wqkvT, b_qkv, qkv);
    transpose_v_kernel<<<BH_ * (T_ / 64), 256, 0, stream>>>(vb, vT);
    flash_kernel<<<BH_ * (T_ / 64), 256, 0, stream>>>(qb, kb, vT, attn);
    gemm_out_kernel<<<dim3(C_ / 128, B_ * T_ / 128), 256, 0, stream>>>(attn, woutT, b_out, out);
}

// Round 3
// 215.358 us; speedup vs baseline: 1.8780x; 1.3454x over previous
//
#include <hip/hip_runtime.h>
#include <hip/hip_bf16.h>

#define B_  4
#define T_  2048
#define C_  1024
#define H_  16
#define D_  64
#define BH_ (B_*H_)

typedef float  f32x4  __attribute__((ext_vector_type(4)));
typedef __bf16 bf16x8 __attribute__((ext_vector_type(8)));
typedef __bf16 bf16x2 __attribute__((ext_vector_type(2)));

static __device__ __forceinline__ ushort f2bf(float f) {
    union { float f; unsigned u; } x; x.f = f;
    unsigned r = ((x.u >> 16) & 1u) + 0x7fffu;
    return (ushort)((x.u + r) >> 16);
}

static __device__ __forceinline__ uint packbf(float a, float b) {
    bf16x2 v = { (__bf16)a, (__bf16)b };   // compiler emits v_cvt_pk_bf16_f32
    return __builtin_bit_cast(uint, v);
}

static __device__ __forceinline__ void gload_lds16(const void* g, void* l) {
    __builtin_amdgcn_global_load_lds(
        (const __attribute__((address_space(1))) unsigned int*)g,
        (__attribute__((address_space(3))) unsigned int*)l, 16, 0, 0);
}

// ---------------- fp32 -> bf16 elementwise (n % 4 == 0) ----------------
__global__ void cvt_kernel(const float* __restrict__ in, ushort* __restrict__ out, int n) {
    int i = (blockIdx.x * blockDim.x + threadIdx.x) * 4;
    if (i < n) {
        float4 v = *(const float4*)(in + i);
        ushort4 o;
        o.x = f2bf(v.x); o.y = f2bf(v.y); o.z = f2bf(v.z); o.w = f2bf(v.w);
        *(ushort4*)(out + i) = o;
    }
}

// ---------------- W (K x N fp32) -> Wt (N x K bf16) ----------------
__global__ void transpose_cvt_kernel(const float* __restrict__ in, ushort* __restrict__ out,
                                     int K, int N) {
    __shared__ float tile[32][33];
    int k0 = blockIdx.y * 32, n0 = blockIdx.x * 32;
    int tx = threadIdx.x & 31, ty = threadIdx.x >> 5;  // 32 x 8
    #pragma unroll
    for (int r = 0; r < 32; r += 8)
        tile[ty + r][tx] = in[(size_t)(k0 + ty + r) * N + n0 + tx];
    __syncthreads();
    #pragma unroll
    for (int r = 0; r < 32; r += 8)
        out[(size_t)(n0 + ty + r) * K + k0 + tx] = f2bf(tile[tx][ty + r]);
}

// ---------------- V (bh, t, d) bf16 -> Vt (bh, d, t) bf16 ----------------
__global__ void transpose_v_kernel(const ushort* __restrict__ v, ushort* __restrict__ vt) {
    __shared__ ushort tile[64][66];
    int bh = blockIdx.x >> 5;
    int t0 = (blockIdx.x & 31) * 64;
    const ushort* src = v  + ((size_t)bh * T_ + t0) * D_;
    ushort*       dst = vt + (size_t)bh * D_ * T_ + t0;
    int tx = threadIdx.x & 63, ty = threadIdx.x >> 6;  // 64 x 4
    #pragma unroll
    for (int r = 0; r < 64; r += 4)
        tile[ty + r][tx] = src[(size_t)(ty + r) * D_ + tx];
    __syncthreads();
    #pragma unroll
    for (int r = 0; r < 64; r += 4)
        dst[(size_t)(ty + r) * T_ + tx] = tile[tx][ty + r];
}

// ---------------- GEMM1: qkv = x @ w_qkv + b, scatter to q/k/v (bh,t,d) ----------------
__global__ __launch_bounds__(256) void gemm_qkv_kernel(
    const ushort* __restrict__ A,    // 8192 x 1024 bf16
    const ushort* __restrict__ Bt,   // 3072 x 1024 bf16 (N x K)
    const float*  __restrict__ bias, // 3072 fp32
    ushort* __restrict__ qkv)        // 3 x (64, 2048, 64) bf16
{
    constexpr int K = 1024;
    __shared__ __align__(16) ushort sA[128 * 64];
    __shared__ __align__(16) ushort sB[128 * 64];
    const int m0 = blockIdx.y * 128, n0 = blockIdx.x * 128;
    const int lane = threadIdx.x & 63, wv = threadIdx.x >> 6;
    const int wm = wv >> 1, wn = wv & 1;
    const int lr = lane & 15, lh = lane >> 4;
    f32x4 acc[4][4] = {};

    for (int kt = 0; kt < K; kt += 64) {
        #pragma unroll
        for (int i = 0; i < 4; ++i) {
            int j = i * 4 + wv;
            int p = j * 64 + lane;
            int row = p >> 3, kc = (p & 7) << 3;
            gload_lds16(A  + (size_t)(m0 + row) * K + kt + kc, &sA[j * 512]);
            gload_lds16(Bt + (size_t)(n0 + row) * K + kt + kc, &sB[j * 512]);
        }
        __syncthreads();
        #pragma unroll
        for (int ks = 0; ks < 2; ++ks) {
            bf16x8 af[4], bfr[4];
            #pragma unroll
            for (int mi = 0; mi < 4; ++mi)
                af[mi] = *(const bf16x8*)&sA[(wm * 64 + mi * 16 + lr) * 64 + ks * 32 + lh * 8];
            #pragma unroll
            for (int ni = 0; ni < 4; ++ni)
                bfr[ni] = *(const bf16x8*)&sB[(wn * 64 + ni * 16 + lr) * 64 + ks * 32 + lh * 8];
            #pragma unroll
            for (int mi = 0; mi < 4; ++mi)
                #pragma unroll
                for (int ni = 0; ni < 4; ++ni)
                    acc[mi][ni] = __builtin_amdgcn_mfma_f32_16x16x32_bf16(af[mi], bfr[ni], acc[mi][ni], 0, 0, 0);
        }
        __syncthreads();
    }

    #pragma unroll
    for (int mi = 0; mi < 4; ++mi) {
        #pragma unroll
        for (int ni = 0; ni < 4; ++ni) {
            int col = n0 + wn * 64 + ni * 16 + lr;
            float bv = bias[col];
            int which = col >> 10;
            int h = (col & 1023) >> 6;
            int d = col & 63;
            #pragma unroll
            for (int r = 0; r < 4; ++r) {
                int row = m0 + wm * 64 + mi * 16 + lh * 4 + r;
                int b = row >> 11, t = row & 2047;
                float v = acc[mi][ni][r] + bv;
                if (which == 0) v *= 0.18033688011112042f;  // 1/sqrt(64) * log2(e) folded into q
                qkv[(size_t)which * (BH_ * T_ * D_) +
                    (((size_t)(b * H_ + h)) * T_ + t) * D_ + d] = f2bf(v);
            }
        }
    }
}

// ---------------- flash attention v3: qt-paired blocks, shared K/V staging ----------------
// q pre-scaled by log2(e)/8 -> softmax in exp2 space.
// Block handles q-tiles qtA = p (short) and qtB = 31-p (long); per-block work
// is 2(p+1) + (31-2p) = 33 tile-units for every p -> perfectly balanced grid.
__global__ __launch_bounds__(256, 4) void flash_kernel(
    const ushort* __restrict__ qb,  // (bh, t, d) bf16
    const ushort* __restrict__ kb,  // (bh, t, d) bf16
    const ushort* __restrict__ vt,  // (bh, d, t) bf16
    ushort* __restrict__ ob)        // (b*t, 1024) bf16
{
    __shared__ __align__(16) ushort sK[2][64 * 64];
    __shared__ __align__(16) ushort sV[2][64 * 64];
    __shared__ __align__(16) ushort sP[4][16 * 64];
    const int bh  = blockIdx.x >> 4;
    const int pr  = blockIdx.x & 15;
    const int qtA = pr, qtB = 31 - pr;
    const int lane = threadIdx.x & 63, wv = threadIdx.x >> 6;
    const int lr = lane & 15, lh = lane >> 4;

    // Q fragments (B-operand): lane lr holds q-row q0+lr, k = lh*8+j
    const ushort* qrowA = qb + ((size_t)bh * T_ + qtA * 64 + wv * 16 + lr) * D_;
    const ushort* qrowB = qb + ((size_t)bh * T_ + qtB * 64 + wv * 16 + lr) * D_;
    bf16x8 qfA0 = *(const bf16x8*)(qrowA + lh * 8);
    bf16x8 qfA1 = *(const bf16x8*)(qrowA + 32 + lh * 8);
    bf16x8 qfB0 = *(const bf16x8*)(qrowB + lh * 8);
    bf16x8 qfB1 = *(const bf16x8*)(qrowB + 32 + lh * 8);

    // staging: chunk j covers LDS rows j*8..j*8+7; source col pre-swizzled
    // so linear LDS dest == swizzled layout (rule #21)
    const int srow = lane >> 3;
    const int scol = ((lane & 7) ^ srow) * 8;
    const ushort* kbase = kb + (size_t)bh * T_ * D_;
    const ushort* vbase = vt + (size_t)bh * D_ * T_;

    // read-side swizzle: all rows read have row%8 == lr%8
    const int sw   = (lr & 7) << 4;
    const int off0 = (16 * lh) ^ sw;
    const int off1 = (64 + 16 * lh) ^ sw;

    f32x4 oA[4] = {}, oB[4] = {};
    float mA = -1e30f, lA = 0.f, mB = -1e30f, lB = 0.f;

    // cross-lane reduce over lanes sharing lr (xor 16 then xor 32)
    auto redmax = [&](float x) {
        x = fmaxf(x, __int_as_float(__builtin_amdgcn_ds_swizzle(__float_as_int(x), 0x401F)));
        x = fmaxf(x, __shfl_xor(x, 32, 64));
        return x;
    };
    auto redsum = [&](float x) {
        x += __int_as_float(__builtin_amdgcn_ds_swizzle(__float_as_int(x), 0x401F));
        x += __shfl_xor(x, 32, 64);
        return x;
    };

    auto tile = [&](f32x4 (&o)[4], float& mrow, float& lsum,
                    const bf16x8& q0f, const bf16x8& q1f,
                    const char* K0, const char* V0, bool diag) {
        // --- QK^T swapped: S^T[k][q]; lane holds q=lr, k = 16nt+4lh+r ---
        f32x4 s[4];
        __builtin_amdgcn_s_setprio(1);
        #pragma unroll
        for (int nt = 0; nt < 4; ++nt) {
            const char* krow = K0 + (nt * 16 + lr) * 128;
            bf16x8 k0 = *(const bf16x8*)(krow + off0);
            bf16x8 k1 = *(const bf16x8*)(krow + off1);
            f32x4 a = {0.f, 0.f, 0.f, 0.f};
            a = __builtin_amdgcn_mfma_f32_16x16x32_bf16(k0, q0f, a, 0, 0, 0);
            a = __builtin_amdgcn_mfma_f32_16x16x32_bf16(k1, q1f, a, 0, 0, 0);
            s[nt] = a;
        }
        __builtin_amdgcn_s_setprio(0);
        if (diag) {   // causal mask: k_local > q_local
            #pragma unroll
            for (int nt = 0; nt < 4; ++nt)
                #pragma unroll
                for (int r = 0; r < 4; ++r)
                    if (nt * 16 + lh * 4 + r > wv * 16 + lr) s[nt][r] = -INFINITY;
        }

        float pmax = fmaxf(fmaxf(fmaxf(s[0][0], s[0][1]), fmaxf(s[0][2], s[0][3])),
                           fmaxf(fmaxf(s[1][0], s[1][1]), fmaxf(s[1][2], s[1][3])));
        pmax = fmaxf(pmax, fmaxf(fmaxf(fmaxf(s[2][0], s[2][1]), fmaxf(s[2][2], s[2][3])),
                                 fmaxf(fmaxf(s[3][0], s[3][1]), fmaxf(s[3][2], s[3][3]))));
        pmax = redmax(pmax);

        // defer-max (T13, THR=8 in exp2 space)
        if (__any(pmax > mrow + 8.f)) {
            float mnew = fmaxf(mrow, pmax);
            float al = __builtin_exp2f(mrow - mnew);
            lsum *= al;
            #pragma unroll
            for (int r = 0; r < 4; ++r) {
                float ar = __shfl(al, lh * 20 + r, 64);  // lane with lr == lh*4+r
                o[0][r] *= ar; o[1][r] *= ar; o[2][r] *= ar; o[3][r] *= ar;
            }
            mrow = mnew;
        }

        float rsum = 0.f;
        uint pk[8];
        #pragma unroll
        for (int nt = 0; nt < 4; ++nt) {
            float p0 = __builtin_exp2f(s[nt][0] - mrow);
            float p1 = __builtin_exp2f(s[nt][1] - mrow);
            float p2 = __builtin_exp2f(s[nt][2] - mrow);
            float p3 = __builtin_exp2f(s[nt][3] - mrow);
            rsum += (p0 + p1) + (p2 + p3);
            pk[nt * 2]     = packbf(p0, p1);
            pk[nt * 2 + 1] = packbf(p2, p3);
        }
        lsum += redsum(rsum);

        // P via per-wave swizzled LDS: 4x b64 write, 2x b128 read
        char* P = (char*)sP[wv];
        {
            char* prow = P + lr * 128;
            #pragma unroll
            for (int nt = 0; nt < 4; ++nt) {
                uint2 w; w.x = pk[nt * 2]; w.y = pk[nt * 2 + 1];
                *(uint2*)(prow + ((32 * nt + 8 * lh) ^ sw)) = w;
            }
        }
        asm volatile("" ::: "memory");
        bf16x8 pf0 = *(const bf16x8*)(P + lr * 128 + off0);
        bf16x8 pf1 = *(const bf16x8*)(P + lr * 128 + off1);

        // PV: O[q][d] += P * V  (o[dt][r]: q = lh*4+r, d = dt*16+lr)
        __builtin_amdgcn_s_setprio(1);
        #pragma unroll
        for (int dt = 0; dt < 4; ++dt) {
            const char* vrow = V0 + (dt * 16 + lr) * 128;
            bf16x8 v0 = *(const bf16x8*)(vrow + off0);
            bf16x8 v1 = *(const bf16x8*)(vrow + off1);
            o[dt] = __builtin_amdgcn_mfma_f32_16x16x32_bf16(pf0, v0, o[dt], 0, 0, 0);
            o[dt] = __builtin_amdgcn_mfma_f32_16x16x32_bf16(pf1, v1, o[dt], 0, 0, 0);
        }
        __builtin_amdgcn_s_setprio(0);
    };

    // prologue: stage tile 0
    #pragma unroll
    for (int i = 0; i < 2; ++i) {
        int j = i * 4 + wv;
        gload_lds16(kbase + (size_t)(j * 8 + srow) * D_ + scol, &sK[0][j * 512]);
        gload_lds16(vbase + (size_t)(j * 8 + srow) * T_ + scol, &sV[0][j * 512]);
    }
    __syncthreads();

    for (int kt = 0; kt <= qtB; ++kt) {
        const int cur = kt & 1;
        if (kt < qtB) {
            const int nb = cur ^ 1;
            #pragma unroll
            for (int i = 0; i < 2; ++i) {
                int j = i * 4 + wv;
                gload_lds16(kbase + (size_t)((kt + 1) * 64 + j * 8 + srow) * D_ + scol, &sK[nb][j * 512]);
                gload_lds16(vbase + (size_t)(j * 8 + srow) * T_ + (kt + 1) * 64 + scol, &sV[nb][j * 512]);
            }
        }
        const char* K0 = (const char*)sK[cur];
        const char* V0 = (const char*)sV[cur];
        if (kt <= qtA) tile(oA, mA, lA, qfA0, qfA1, K0, V0, kt == qtA);
        tile(oB, mB, lB, qfB0, qfB1, K0, V0, kt == qtB);
        __syncthreads();
    }

    const int b = bh >> 4, h = bh & 15;
    auto writeout = [&](f32x4 (&o)[4], float lsum, int q0) {
        float inv = 1.f / lsum;
        #pragma unroll
        for (int r = 0; r < 4; ++r) {
            float ir = __shfl(inv, lh * 20 + r, 64);
            int q = q0 + lh * 4 + r;
            #pragma unroll
            for (int dt = 0; dt < 4; ++dt)
                ob[((size_t)b * T_ + q) * C_ + h * 64 + dt * 16 + lr] = f2bf(o[dt][r] * ir);
        }
    };
    writeout(oA, lA, qtA * 64 + wv * 16);
    writeout(oB, lB, qtB * 64 + wv * 16);
}

// ---------------- GEMM2: out = attn @ w_out + b_out (fp32 out) ----------------
__global__ __launch_bounds__(256) void gemm_out_kernel(
    const ushort* __restrict__ A,    // 8192 x 1024 bf16
    const ushort* __restrict__ Bt,   // 1024 x 1024 bf16 (N x K)
    const float*  __restrict__ bias, // 1024 fp32
    float* __restrict__ Cout)        // 8192 x 1024 fp32
{
    constexpr int K = 1024;
    __shared__ __align__(16) ushort sA[128 * 64];
    __shared__ __align__(16) ushort sB[128 * 64];
    const int m0 = blockIdx.y * 128, n0 = blockIdx.x * 128;
    const int lane = threadIdx.x & 63, wv = threadIdx.x >> 6;
    const int wm = wv >> 1, wn = wv & 1;
    const int lr = lane & 15, lh = lane >> 4;
    f32x4 acc[4][4] = {};

    for (int kt = 0; kt < K; kt += 64) {
        #pragma unroll
        for (int i = 0; i < 4; ++i) {
            int j = i * 4 + wv;
            int p = j * 64 + lane;
            int row = p >> 3, kc = (p & 7) << 3;
            gload_lds16(A  + (size_t)(m0 + row) * K + kt + kc, &sA[j * 512]);
            gload_lds16(Bt + (size_t)(n0 + row) * K + kt + kc, &sB[j * 512]);
        }
        __syncthreads();
        #pragma unroll
        for (int ks = 0; ks < 2; ++ks) {
            bf16x8 af[4], bfr[4];
            #pragma unroll
            for (int mi = 0; mi < 4; ++mi)
                af[mi] = *(const bf16x8*)&sA[(wm * 64 + mi * 16 + lr) * 64 + ks * 32 + lh * 8];
            #pragma unroll
            for (int ni = 0; ni < 4; ++ni)
                bfr[ni] = *(const bf16x8*)&sB[(wn * 64 + ni * 16 + lr) * 64 + ks * 32 + lh * 8];
            #pragma unroll
            for (int mi = 0; mi < 4; ++mi)
                #pragma unroll
                for (int ni = 0; ni < 4; ++ni)
                    acc[mi][ni] = __builtin_amdgcn_mfma_f32_16x16x32_bf16(af[mi], bfr[ni], acc[mi][ni], 0, 0, 0);
        }
        __syncthreads();
    }

    #pragma unroll
    for (int mi = 0; mi < 4; ++mi) {
        #pragma unroll
        for (int ni = 0; ni < 4; ++ni) {
            int col = n0 + wn * 64 + ni * 16 + lr;
            float bv = bias[col];
            #pragma unroll
            for (int r = 0; r < 4; ++r) {
                int row = m0 + wm * 64 + mi * 16 + lh * 4 + r;
                Cout[(size_t)row * C_ + col] = acc[mi][ni][r] + bv;
            }
        }
    }
}

extern "C" void kernel_launch(void* const* d_in, const int* in_sizes, int n_in,
                              void* d_out, int out_size, void* d_ws, size_t ws_size,
                              hipStream_t stream) {
    const float* x     = (const float*)d_in[0];
    const float* w_qkv = (const float*)d_in[1];
    const float* b_qkv = (const float*)d_in[2];
    const float* w_out = (const float*)d_in[3];
    const float* b_out = (const float*)d_in[4];
    float* out = (float*)d_out;

    char* ws = (char*)d_ws;
    ushort* xb     = (ushort*)(ws + 0);           // 16 MB (aliased: attn out reuses after GEMM1)
    ushort* wqkvT  = (ushort*)(ws + 16777216);    // 6 MB
    ushort* woutT  = (ushort*)(ws + 23068672);    // 2 MB
    ushort* qkv    = (ushort*)(ws + 25165824);    // 48 MB
    ushort* vT     = (ushort*)(ws + 75497472);    // 16 MB
    ushort* attn   = xb;
    ushort* qb = qkv;
    ushort* kb = qkv + (size_t)BH_ * T_ * D_;
    ushort* vb = qkv + (size_t)2 * BH_ * T_ * D_;

    const int nx = B_ * T_ * C_;
    cvt_kernel<<<nx / 4 / 256, 256, 0, stream>>>(x, xb, nx);
    transpose_cvt_kernel<<<dim3(3 * C_ / 32, C_ / 32), 256, 0, stream>>>(w_qkv, wqkvT, C_, 3 * C_);
    transpose_cvt_kernel<<<dim3(C_ / 32, C_ / 32), 256, 0, stream>>>(w_out, woutT, C_, C_);
    gemm_qkv_kernel<<<dim3(3 * C_ / 128, B_ * T_ / 128), 256, 0, stream>>>(xb, wqkvT, b_qkv, qkv);
    transpose_v_kernel<<<BH_ * (T_ / 64), 256, 0, stream>>>(vb, vT);
    flash_kernel<<<BH_ * 16, 256, 0, stream>>>(qb, kb, vT, attn);
    gemm_out_kernel<<<dim3(C_ / 128, B_ * T_ / 128), 256, 0, stream>>>(attn, woutT, b_out, out);
}